// Round 9
// baseline (149.378 us; speedup 1.0000x reference)
//
#include <hip/hip_runtime.h>
#include <math.h>

// (B,P,V,F,H) = (32,512,32,16,64). Round 13: zero-global-chain + occupancy.
// Unified model fitting v5-v12: throughput = resident_waves / wave_lifetime;
// lifetime dominated by SERIAL memory stalls on the per-bp chain (per-ki
// W-loads ~200cy x16, LDS turnarounds ~150cy, X ~900cy, v12's ~192 scalar
// bias loads). Every prior round improved one factor, paid it back in the
// other (v6: +occupancy +spill-stalls; v12: -LDS-turnaround +W-stalls).
// This version does both:
//  - keep v12's HW-validated transposed chain (h^T via mfma(A=W,B=h^T);
//    in-register shfl exchange; packed-f16 epilogue; pool = masked 5-step
//    shfl reduce) — no h LDS, no barriers in the chain;
//  - stage W (34816 B) + bias-C table (768 B) into LDS ONCE per block via
//    global_load_lds: after the prologue the chain touches NO global memory
//    (W = prefetchable ds_read_b128; bias = lane-uniform LDS broadcast);
//  - LDS 35.6 KB -> 4 blocks/CU; __launch_bounds__(256,4) -> 16 waves/CU
//    (50%), ~2x v10's residency; est. regs ~110 < 128 cap (v12: 44 arch).
// MFMA 32x32x16_f16: A[m=l&31][k=8*(l>>5)+j], B[k][n=l&31],
//                    D[row=(r&3)+8*(r>>2)+4*(l>>5)][col=l&31].
namespace {

typedef _Float16 f16x8 __attribute__((ext_vector_type(8)));
typedef _Float16 f16x2 __attribute__((ext_vector_type(2)));
typedef float    f32x16 __attribute__((ext_vector_type(16)));
typedef unsigned int uint;

__device__ __forceinline__ uint pkrtz(float a, float b) {
    return __builtin_bit_cast(uint, __builtin_amdgcn_cvt_pkrtz(a, b));
}
__device__ __forceinline__ uint pk_add(uint a, uint b) {
    uint r; asm("v_pk_add_f16 %0, %1, %2" : "=v"(r) : "v"(a), "v"(b)); return r;
}
__device__ __forceinline__ uint pk_mul(uint a, uint b) {
    uint r; asm("v_pk_mul_f16 %0, %1, %2" : "=v"(r) : "v"(a), "v"(b)); return r;
}
__device__ __forceinline__ uint pk_max(uint a, uint b) {
    uint r; asm("v_pk_max_f16 %0, %1, %2" : "=v"(r) : "v"(a), "v"(b)); return r;
}

// ---- prep: W frags (identical to v10-v12, HW-validated), bias-C table,
//      per-bp u32 masks ----
// W frag f: 0..1 = W1; 2..17 = W2 (ki=(f-2)>>1, nt2=(f-2)&1); 18..33 = W3.
// Lane l of frag f holds W[32*nt2 + (l&31)][16ki + 8*(l>>5)+j].
// bias-C: wsB[layer*64 + hb*32 + n2*16 + r] = B_layer[(r&3)+8*(r>>2)+4hb+32n2]
// (so C[r] for the transposed MFMA is a contiguous 16-float LDS read).
__global__ void prep_pack(const float* __restrict__ W1, const float* __restrict__ W2,
                          const float* __restrict__ W3, const float* __restrict__ B1,
                          const float* __restrict__ B2, const float* __restrict__ B3,
                          const int* __restrict__ M,
                          unsigned short* __restrict__ wsW, float* __restrict__ wsB,
                          uint* __restrict__ wsM)
{
    int t = blockIdx.x * blockDim.x + threadIdx.x;
    if (t < 34 * 64) {
        int f = t >> 6, l = t & 63, nb = l & 31, kg = l >> 5;
        const float* src; int K, ki, nt2;
        if (f < 2)       { src = W1; K = 16;  ki = 0;           nt2 = f; }
        else if (f < 18) { int g = f - 2;  src = W2; K = 128; ki = g >> 1; nt2 = g & 1; }
        else             { int g = f - 18; src = W3; K = 128; ki = g >> 1; nt2 = g & 1; }
        const float* s = src + (size_t)(32 * nt2 + nb) * K + 16 * ki + 8 * kg;
        uint4 q;
        q.x = pkrtz(s[0], s[1]); q.y = pkrtz(s[2], s[3]);
        q.z = pkrtz(s[4], s[5]); q.w = pkrtz(s[6], s[7]);
        *(uint4*)(wsW + (size_t)f * 512 + l * 8) = q;
    } else if (t < 34 * 64 + 192) {
        int i = t - 34 * 64;
        int layer = i >> 6, rem = i & 63;
        int hb = rem >> 5, n2 = (rem >> 4) & 1, r = rem & 15;
        const float* B = (layer == 0) ? B1 : (layer == 1) ? B2 : B3;
        wsB[i] = B[(r & 3) + 8 * (r >> 2) + 4 * hb + 32 * n2];
    } else if (t < 34 * 64 + 192 + 16384) {
        int bp = t - (34 * 64 + 192);
        const int4* mp = (const int4*)(M + bp * 32);
        uint bits = 0;
        #pragma unroll
        for (int i = 0; i < 8; ++i) {
            int4 v = mp[i];
            bits |= ((v.x ? 1u : 0u) | (v.y ? 2u : 0u) |
                     (v.z ? 4u : 0u) | (v.w ? 8u : 0u)) << (4 * i);
        }
        wsM[bp] = bits;
    }
}

__global__ __launch_bounds__(256, 4) void fused_mlp_v13(
    const float* __restrict__ X, const uint* __restrict__ MPK,
    const unsigned short* __restrict__ WFg, const float* __restrict__ BCg,
    float* __restrict__ OUT)
{
    __shared__ __align__(16) unsigned short sWF[34 * 512];  // 34816 B
    __shared__ __align__(16) float sBC[192];                //   768 B

    const int t = threadIdx.x, w = t >> 6, l = t & 63;
    const int vr = l & 31, hb = l >> 5;
    const size_t bp = (size_t)blockIdx.x * 4 + w;   // one bp per wave

    // ---- stage W frags into LDS (waves interleaved, 16 B/lane) ----
    #pragma unroll
    for (int i = 0; i < 9; ++i) {
        int f = w + 4 * i;
        if (f < 34)
            __builtin_amdgcn_global_load_lds(
                (const __attribute__((address_space(1))) void*)(WFg + (size_t)f * 512 + l * 8),
                (__attribute__((address_space(3))) void*)&sWF[f * 512], 16, 0, 0);
    }
    // ---- stage bias-C table (wave 3; 3 x 64 dwords) ----
    if (w == 3) {
        #pragma unroll
        for (int j = 0; j < 3; ++j)
            __builtin_amdgcn_global_load_lds(
                (const __attribute__((address_space(1))) void*)(BCg + j * 64 + l),
                (__attribute__((address_space(3))) void*)&sBC[j * 64], 4, 0, 0);
    }

    const uint SL2 = pkrtz(0.01f, 0.01f);
    const uint mk = MPK[bp];
    const bool anyv = (mk != 0u);
    const uint adm = ((mk >> vr) & 1u) ? 0u : 0xFC00FC00u;   // 2x f16 -inf

    // ---- X as B-frag: B[k=8hb+j][n=vr] = X[bp][vr][8hb+j] ----
    f16x8 bfx;
    {
        const float4* xp = (const float4*)(X + ((size_t)bp * 32 + vr) * 16 + 8 * hb);
        float4 x0 = xp[0], x1 = xp[1];
        uint4 q;
        q.x = pkrtz(x0.x, x0.y); q.y = pkrtz(x0.z, x0.w);
        q.z = pkrtz(x1.x, x1.y); q.w = pkrtz(x1.z, x1.w);
        bfx = __builtin_bit_cast(f16x8, q);
    }

    __syncthreads();   // staging complete; only barrier in the kernel

    // bias C-operand from LDS (lane-uniform per hb-half: broadcast reads)
    auto loadC = [&](int layer, int n2) -> f32x16 {
        const float* p = sBC + layer * 64 + hb * 32 + n2 * 16;
        f32x16 cc;
        #pragma unroll
        for (int r4 = 0; r4 < 4; ++r4) {
            float4 v = *(const float4*)(p + 4 * r4);
            cc[4 * r4 + 0] = v.x; cc[4 * r4 + 1] = v.y;
            cc[4 * r4 + 2] = v.z; cc[4 * r4 + 3] = v.w;
        }
        return cc;
    };

    auto red5 = [&](uint v) -> uint {
        v = pk_max(v, (uint)__shfl_xor((int)v, 1));
        v = pk_max(v, (uint)__shfl_xor((int)v, 2));
        v = pk_max(v, (uint)__shfl_xor((int)v, 4));
        v = pk_max(v, (uint)__shfl_xor((int)v, 8));
        v = pk_max(v, (uint)__shfl_xor((int)v, 16));
        return v;
    };

    f32x16 acc0, acc1;
    uint P[2][4][2];    // packed h:    P[n2][g][b] = feats (8g+4hb+2b, +1)
    uint PL[2][4][2];   // packed pool: same layout, valid in all lanes

    auto epilogue = [&]() {
        #pragma unroll
        for (int n2 = 0; n2 < 2; ++n2) {
            #pragma unroll
            for (int g = 0; g < 4; ++g)
                #pragma unroll
                for (int b = 0; b < 2; ++b) {
                    const f32x16& A = n2 ? acc1 : acc0;
                    uint d = pkrtz(A[4 * g + 2 * b], A[4 * g + 2 * b + 1]);
                    d = pk_max(d, pk_mul(d, SL2));        // packed lrelu
                    P[n2][g][b] = d;
                    uint m = red5(pk_add(d, adm));
                    PL[n2][g][b] = anyv ? m : 0u;
                }
        }
    };

    // K=128 layer: s=0..3 from P (out half), s=4..7 from PL (rep half);
    // B[s][a] = S[.][2(s&1)+hb'][a&1] from half a>>1 (v12, HW-validated).
    auto layerK = [&](int fb, int layer) {
        f32x16 cb0 = loadC(layer, 0), cb1 = loadC(layer, 1);
        f32x16 a0, a1;
        #pragma unroll
        for (int s = 0; s < 8; ++s) {
            const uint (&S)[2][4][2] = (s < 4) ? P : PL;
            const int p = s & 3, n2s = p >> 1, sg = p & 1;
            uint s00 = S[n2s][2 * sg + 0][0], s01 = S[n2s][2 * sg + 0][1];
            uint s10 = S[n2s][2 * sg + 1][0], s11 = S[n2s][2 * sg + 1][1];
            uint w0 = (uint)__shfl_xor((int)s00, 32);
            uint w1 = (uint)__shfl_xor((int)s01, 32);
            uint w2 = (uint)__shfl_xor((int)s10, 32);
            uint w3 = (uint)__shfl_xor((int)s11, 32);
            uint4 q;
            q.x = hb ? w2 : s00;
            q.y = hb ? w3 : s01;
            q.z = hb ? s10 : w0;
            q.w = hb ? s11 : w1;
            f16x8 bf = __builtin_bit_cast(f16x8, q);
            const _Float16* wp = (const _Float16*)sWF + (size_t)(fb + 2 * s) * 512 + l * 8;
            f16x8 wA0 = *(const f16x8*)wp;
            f16x8 wA1 = *(const f16x8*)(wp + 512);
            a0 = __builtin_amdgcn_mfma_f32_32x32x16_f16(wA0, bf, s ? a0 : cb0, 0, 0, 0);
            a1 = __builtin_amdgcn_mfma_f32_32x32x16_f16(wA1, bf, s ? a1 : cb1, 0, 0, 0);
        }
        acc0 = a0; acc1 = a1;
    };

    // ---- layer 1 (K=16, single step; W1 = LDS frags 0,1) ----
    {
        const _Float16* wp = (const _Float16*)sWF + l * 8;
        f16x8 wA0 = *(const f16x8*)wp;
        f16x8 wA1 = *(const f16x8*)(wp + 512);
        f32x16 cb0 = loadC(0, 0), cb1 = loadC(0, 1);
        acc0 = __builtin_amdgcn_mfma_f32_32x32x16_f16(wA0, bfx, cb0, 0, 0, 0);
        acc1 = __builtin_amdgcn_mfma_f32_32x32x16_f16(wA1, bfx, cb1, 0, 0, 0);
    }

    epilogue();          // h1 -> P, PL
    layerK(2, 1);        // layer 2 (bias B2)
    epilogue();          // h2 -> P, PL
    layerK(18, 2);       // layer 3 (bias B3)
    epilogue();          // h3 -> PL (final pools)

    // ---- final output = pool3; one writer lane per half ----
    if (vr == 0) {
        float* o = OUT + bp * 64 + 4 * hb;
        #pragma unroll
        for (int n2 = 0; n2 < 2; ++n2)
            #pragma unroll
            for (int g = 0; g < 4; ++g)
                #pragma unroll
                for (int b = 0; b < 2; ++b) {
                    f16x2 h2 = __builtin_bit_cast(f16x2, PL[n2][g][b]);
                    float2 st; st.x = (float)h2[0]; st.y = (float)h2[1];
                    *(float2*)(o + 32 * n2 + 8 * g + 2 * b) = st;
                }
    }
}
} // namespace

extern "C" void kernel_launch(void* const* d_in, const int* in_sizes, int n_in,
                              void* d_out, int out_size, void* d_ws, size_t ws_size,
                              hipStream_t stream) {
    (void)in_sizes; (void)n_in; (void)ws_size; (void)out_size;
    const float* X  = (const float*)d_in[0];
    const int*   M  = (const int*)d_in[1];
    const float* W1 = (const float*)d_in[2];
    const float* B1 = (const float*)d_in[3];
    const float* W2 = (const float*)d_in[4];
    const float* B2 = (const float*)d_in[5];
    const float* W3 = (const float*)d_in[6];
    const float* B3 = (const float*)d_in[7];
    float* OUT = (float*)d_out;

    unsigned short* WF  = (unsigned short*)d_ws;              // 34816 B
    float*          BC  = (float*)((char*)d_ws + 34816);      //   768 B
    uint*           MPK = (uint*)((char*)d_ws + 35584);       // 65536 B

    prep_pack<<<(34 * 64 + 192 + 16384 + 255) / 256, 256, 0, stream>>>(
        W1, W2, W3, B1, B2, B3, M, WF, BC, MPK);
    // 4096 blocks x 4 waves; one bp per wave; zero global access post-prologue
    fused_mlp_v13<<<4096, 256, 0, stream>>>(X, MPK, WF, BC, OUT);
}

// Round 10
// 116.086 us; speedup vs baseline: 1.2868x; 1.2868x over previous
//
#include <hip/hip_runtime.h>
#include <math.h>

// (B,P,V,F,H) = (32,512,32,16,64). Round 14: v10 + CONVOY-BREAKING stagger.
// Eight falsified single-pipe theories. The model that fits ALL of v5-v13:
// per-CU pipe budgets SUM (v10: MFMA 6 + VALU 13 + DS 18 + L1 7 ~= 46 meas;
// v12/13: shfl-latency chains balloon the DS term -> 70/73; v9: loop VALU ->
// 53), because waves run in CONVOY: identical code, identical latencies, no
// barriers, no data-dependent branches => all waves on a CU sit in the same
// phase simultaneously; each phase saturates one pipe while others idle.
// Explains occupancy-invariance (v6/v7: more waves = proportionally longer
// phases) and why v11's source-interleave failed (compiler re-clusters into
// phases; identical emitted code keeps identical timing).
// Experiment (single variable vs v10): one-time prologue stagger,
// hash(waveid)&15 slots x s_sleep(2) (~128cy) = 0..1920cy spread ~ one
// per-bp phase period. No downstream resync points -> stagger persists;
// waves occupy different phases -> pipes overlap. Cost if wrong: ~0.4us.
// Everything else is v10 VERBATIM (passed, 46.2us, clean counters).
namespace {

typedef _Float16 f16x8 __attribute__((ext_vector_type(8)));
typedef _Float16 f16x2 __attribute__((ext_vector_type(2)));
typedef float    f32x16 __attribute__((ext_vector_type(16)));
typedef unsigned int uint;

__device__ __forceinline__ uint pkrtz(float a, float b) {
    return __builtin_bit_cast(uint, __builtin_amdgcn_cvt_pkrtz(a, b));
}
__device__ __forceinline__ uint pk_add(uint a, uint b) {
    uint r; asm("v_pk_add_f16 %0, %1, %2" : "=v"(r) : "v"(a), "v"(b)); return r;
}
__device__ __forceinline__ uint pk_mul(uint a, uint b) {
    uint r; asm("v_pk_mul_f16 %0, %1, %2" : "=v"(r) : "v"(a), "v"(b)); return r;
}
__device__ __forceinline__ uint pk_max(uint a, uint b) {
    uint r; asm("v_pk_max_f16 %0, %1, %2" : "=v"(r) : "v"(a), "v"(b)); return r;
}

// ---- prep: pack W1/W2/W3 as f16 32x32x16 B-frags + per-bp u32 masks ----
// frag f: 0..1 = W1 (ki=0, nt2=f); 2..17 = W2 (ki=(f-2)>>1, nt2=(f-2)&1);
// 18..33 = W3. Lane l of frag f holds W[32*nt2 + (l&31)][16ki + 8*(l>>5)+j].
__global__ void prep_pack(const float* __restrict__ W1, const float* __restrict__ W2,
                          const float* __restrict__ W3, const int* __restrict__ M,
                          unsigned short* __restrict__ wsW, uint* __restrict__ wsM)
{
    int t = blockIdx.x * blockDim.x + threadIdx.x;
    if (t < 34 * 64) {
        int f = t >> 6, l = t & 63, nb = l & 31, kg = l >> 5;
        const float* src; int K, ki, nt2;
        if (f < 2)       { src = W1; K = 16;  ki = 0;           nt2 = f; }
        else if (f < 18) { int g = f - 2;  src = W2; K = 128; ki = g >> 1; nt2 = g & 1; }
        else             { int g = f - 18; src = W3; K = 128; ki = g >> 1; nt2 = g & 1; }
        const float* s = src + (size_t)(32 * nt2 + nb) * K + 16 * ki + 8 * kg;
        uint4 q;
        q.x = pkrtz(s[0], s[1]); q.y = pkrtz(s[2], s[3]);
        q.z = pkrtz(s[4], s[5]); q.w = pkrtz(s[6], s[7]);
        *(uint4*)(wsW + (size_t)f * 512 + l * 8) = q;
    } else if (t < 34 * 64 + 16384) {
        int bp = t - 34 * 64;
        const int4* mp = (const int4*)(M + bp * 32);
        uint bits = 0;
        #pragma unroll
        for (int i = 0; i < 8; ++i) {
            int4 v = mp[i];
            bits |= ((v.x ? 1u : 0u) | (v.y ? 2u : 0u) |
                     (v.z ? 4u : 0u) | (v.w ? 8u : 0u)) << (4 * i);
        }
        wsM[bp] = bits;
    }
}

__global__ __launch_bounds__(256, 3) void fused_mlp_v14(
    const float* __restrict__ X, const uint* __restrict__ MPK,
    const unsigned short* __restrict__ WF,
    const float* __restrict__ B1, const float* __restrict__ B2,
    const float* __restrict__ B3, float* __restrict__ OUT)
{
    __shared__ __align__(16) unsigned char sXb[4][2][4096];  // 32768 B
    __shared__ __align__(16) _Float16 sP[4][2][64];          //  1024 B

    const int t = threadIdx.x, w = t >> 6, l = t & 63;
    const int hb = l >> 5, mtl = (l >> 4) & 1;
    const size_t bp0 = (size_t)blockIdx.x * 8 + w * 2;

    // ---- CONVOY BREAKER: one-time per-wave stagger, 16 slots x ~128cy ----
    {
        uint wgid = (uint)blockIdx.x * 4u + (uint)w;
        uint sk = (wgid ^ (wgid >> 3) ^ (wgid >> 6)) & 15u;
        #pragma unroll 1
        for (uint i = 0; i < sk; ++i) __builtin_amdgcn_s_sleep(2);
    }

    unsigned char* sb[2] = { &sXb[w][0][0], &sXb[w][1][0] };
    _Float16*     pl[2] = { &sP[w][0][0],  &sP[w][1][0]  };

    // write base (byte): rows m..m+3 at col n -> one b64. Lane-const XOR
    // swizzle component folded in; nt2 component via wb1 = (wb0+512)^64.
    uint wb0 = (uint)((l & 7) * 32 + mtl * 256 + ((l >> 3) & 1) * 1024 + hb * 8);
    wb0 ^= (uint)(mtl << 5);
    const uint wb1 = (wb0 + 512u) ^ 64u;
    // read base: + 256*ki + 32*(j^ki) gives dword of (m&~1,m|1) at feature n.
    const uint rb = (uint)(mtl * 2048 + hb * 1024 + ((l & 15) >> 1) * 4);
    const uint sel = (l & 1) ? 0x07060302u : 0x05040100u;  // pick own f16 half
    const uint SL2 = pkrtz(0.01f, 0.01f);

    // ---- masks: packed -inf addends for pool (pairs of rows m,m+1) ----
    bool anyv[2]; uint adm[2][4][2];
    #pragma unroll
    for (int u = 0; u < 2; ++u) {
        uint mk = MPK[bp0 + u];
        anyv[u] = (mk != 0u);
        #pragma unroll
        for (int g = 0; g < 4; ++g) {   // rows 8g+4hb .. +3
            uint nib = (mk >> (8 * g + 4 * hb)) & 15u;
            adm[u][g][0] = (nib & 1u ? 0u : 0xFC00u) | (nib & 2u ? 0u : 0xFC000000u);
            adm[u][g][1] = (nib & 4u ? 0u : 0xFC00u) | (nib & 8u ? 0u : 0xFC000000u);
        }
    }

    // ---- X -> layer-1 A-frags (f16, rtz) ----
    f16x8 a1f[2];
    #pragma unroll
    for (int u = 0; u < 2; ++u) {
        const float4* xp = (const float4*)(X + ((bp0 + u) * 32 + (l & 31)) * 16 + 8 * hb);
        float4 x0 = xp[0], x1 = xp[1];
        uint4 q;
        q.x = pkrtz(x0.x, x0.y); q.y = pkrtz(x0.z, x0.w);
        q.z = pkrtz(x1.x, x1.y); q.w = pkrtz(x1.z, x1.w);
        a1f[u] = __builtin_bit_cast(f16x8, q);
    }

    // persistent zero C-input (16 regs, init once)
    f32x16 zc;
    #pragma unroll
    for (int i = 0; i < 16; ++i) zc[i] = 0.f;

    f32x16 acc[2][2];   // [u][nt2]

    // ---- layer 1 (K=16, one 32x32x16 step, no padding) ----
    {
        const _Float16* wp = (const _Float16*)WF + l * 8;
        f16x8 wf0 = *(const f16x8*)wp;
        f16x8 wf1 = *(const f16x8*)(wp + 512);
        #pragma unroll
        for (int u = 0; u < 2; ++u) {
            acc[u][0] = __builtin_amdgcn_mfma_f32_32x32x16_f16(a1f[u], wf0, zc, 0, 0, 0);
            acc[u][1] = __builtin_amdgcn_mfma_f32_32x32x16_f16(a1f[u], wf1, zc, 0, 0, 0);
        }
    }

    // ---- epilogue: +bias, lrelu, (store h to swizzled LDS), masked pool ----
    auto epi = [&](int u, const float* __restrict__ Bp, bool dostore) {
        unsigned char* sbu = sb[u];
        _Float16* plu = pl[u];
        #pragma unroll
        for (int nt2 = 0; nt2 < 2; ++nt2) {
            float bsc = Bp[32 * nt2 + (l & 31)];
            uint bpk = pkrtz(bsc, bsc);
            uint base = nt2 ? wb1 : wb0;
            uint pp = 0xFC00FC00u;   // (-inf, -inf)
            #pragma unroll
            for (int g = 0; g < 4; ++g) {   // rows m = 8g+4hb .. +3
                uint d01 = pkrtz(acc[u][nt2][4 * g + 0], acc[u][nt2][4 * g + 1]);
                uint d23 = pkrtz(acc[u][nt2][4 * g + 2], acc[u][nt2][4 * g + 3]);
                d01 = pk_add(d01, bpk);  d23 = pk_add(d23, bpk);
                d01 = pk_max(d01, pk_mul(d01, SL2));      // packed lrelu
                d23 = pk_max(d23, pk_mul(d23, SL2));
                if (dostore) {
                    uint2 st; st.x = d01; st.y = d23;
                    *(uint2*)(sbu + base + (g >> 1) * 2048 + (g & 1) * 16) = st;
                }
                pp = pk_max(pp, pk_add(d01, adm[u][g][0]));
                pp = pk_max(pp, pk_add(d23, adm[u][g][1]));
            }
            f16x2 ph = __builtin_bit_cast(f16x2, pp);
            float pv = fmaxf((float)ph[0], (float)ph[1]);
            pv = fmaxf(pv, __shfl_xor(pv, 32));   // merge other hb half
            pv = anyv[u] ? pv : 0.f;
            if (dostore) {
                if (l < 32) plu[32 * nt2 + (l & 31)] = (_Float16)pv;
            } else {
                if (l < 32) OUT[(bp0 + u) * 64 + 32 * nt2 + (l & 31)] = pv;
            }
        }
    };

    // ---- K=128 layer: ki 0..3 from swizzled h, ki 4..7 from pool bcast ----
    auto layerK = [&](int fb) {
        #pragma unroll
        for (int ki = 0; ki < 8; ++ki) {
            const _Float16* wp = (const _Float16*)WF + (size_t)(fb + 2 * ki) * 512 + l * 8;
            f16x8 wf0 = *(const f16x8*)wp;
            f16x8 wf1 = *(const f16x8*)(wp + 512);
            #pragma unroll
            for (int u = 0; u < 2; ++u) {
                f16x8 a;
                if (ki < 4) {
                    const unsigned char* p = sb[u] + rb + 256 * ki;
                    uint F0 = *(const uint*)(p + 32 * (0 ^ ki));
                    uint F1 = *(const uint*)(p + 32 * (1 ^ ki));
                    uint F2 = *(const uint*)(p + 32 * (2 ^ ki));
                    uint F3 = *(const uint*)(p + 32 * (3 ^ ki));
                    uint F4 = *(const uint*)(p + 32 * (4 ^ ki));
                    uint F5 = *(const uint*)(p + 32 * (5 ^ ki));
                    uint F6 = *(const uint*)(p + 32 * (6 ^ ki));
                    uint F7 = *(const uint*)(p + 32 * (7 ^ ki));
                    uint4 q;
                    q.x = __builtin_amdgcn_perm(F1, F0, sel);
                    q.y = __builtin_amdgcn_perm(F3, F2, sel);
                    q.z = __builtin_amdgcn_perm(F5, F4, sel);
                    q.w = __builtin_amdgcn_perm(F7, F6, sel);
                    a = __builtin_bit_cast(f16x8, q);
                } else {
                    a = *(const f16x8*)(pl[u] + 16 * (ki - 4) + 8 * hb);  // bcast
                }
                acc[u][0] = __builtin_amdgcn_mfma_f32_32x32x16_f16(
                    a, wf0, ki == 0 ? zc : acc[u][0], 0, 0, 0);
                acc[u][1] = __builtin_amdgcn_mfma_f32_32x32x16_f16(
                    a, wf1, ki == 0 ? zc : acc[u][1], 0, 0, 0);
            }
        }
    };

    epi(0, B1, true);  epi(1, B1, true);
    layerK(2);
    epi(0, B2, true);  epi(1, B2, true);
    layerK(18);
    epi(0, B3, false); epi(1, B3, false);   // layer-3 pool == final output
}
} // namespace

extern "C" void kernel_launch(void* const* d_in, const int* in_sizes, int n_in,
                              void* d_out, int out_size, void* d_ws, size_t ws_size,
                              hipStream_t stream) {
    (void)in_sizes; (void)n_in; (void)ws_size; (void)out_size;
    const float* X  = (const float*)d_in[0];
    const int*   M  = (const int*)d_in[1];
    const float* W1 = (const float*)d_in[2];
    const float* B1 = (const float*)d_in[3];
    const float* W2 = (const float*)d_in[4];
    const float* B2 = (const float*)d_in[5];
    const float* W3 = (const float*)d_in[6];
    const float* B3 = (const float*)d_in[7];
    float* OUT = (float*)d_out;

    unsigned short* WF  = (unsigned short*)d_ws;              // 34816 B
    uint*           MPK = (uint*)((char*)d_ws + 34816);       // 65536 B

    prep_pack<<<(34 * 64 + 16384 + 255) / 256, 256, 0, stream>>>(W1, W2, W3, M, WF, MPK);
    // 2048 blocks x 4 waves x 2 bp = 16384 bp; two bp per wave
    fused_mlp_v14<<<2048, 256, 0, stream>>>(X, MPK, WF, B1, B2, B3, OUT);
}